// Round 8
// baseline (744.347 us; speedup 1.0000x reference)
//
#include <hip/hip_runtime.h>
#include <hip/hip_bf16.h>

#define NN 50000
#define NE 800000
#define DD 64
#define NL 3

__device__ __forceinline__ int rlanei(int v, int l) {
    return __builtin_amdgcn_readlane(v, l);
}
__device__ __forceinline__ float rlane(float v, int l) {
    return __int_as_float(__builtin_amdgcn_readlane(__float_as_int(v), l));
}

// ---------------------------------------------------------------------------
// CSR build, step 1: in-degree histogram. 4 edges/thread via int4 loads.
// ---------------------------------------------------------------------------
__global__ void hist_kernel(const int* __restrict__ dst, int* __restrict__ deg) {
    int t = blockIdx.x * blockDim.x + threadIdx.x;
    int e = t * 4;
    if (e + 4 <= NE) {
        int4 d4 = *reinterpret_cast<const int4*>(dst + e);
        atomicAdd(&deg[d4.x], 1);
        atomicAdd(&deg[d4.y], 1);
        atomicAdd(&deg[d4.z], 1);
        atomicAdd(&deg[d4.w], 1);
    } else {
        for (int i = e; i < NE; ++i) atomicAdd(&deg[dst[i]], 1);
    }
}

// ---------------------------------------------------------------------------
// CSR build, step 2: unordered segment allocation (order irrelevant for a
// sum): wave-level __shfl_up scan + one atomicAdd per wave on a counter.
// ---------------------------------------------------------------------------
__global__ void alloc_kernel(const int* __restrict__ deg,
                             int* __restrict__ row_start,
                             int* __restrict__ cursor,
                             int* __restrict__ counter) {
    int n = blockIdx.x * blockDim.x + threadIdx.x;
    int lane = threadIdx.x & 63;
    int d = (n < NN) ? deg[n] : 0;
    int s = d;
    #pragma unroll
    for (int off = 1; off < 64; off <<= 1) {
        int t = __shfl_up(s, off);
        if (lane >= off) s += t;
    }
    int total = __shfl(s, 63);
    int base = 0;
    if (lane == 63) base = atomicAdd(counter, total);
    base = __shfl(base, 63);
    int my = base + s - d;
    if (n < NN) { row_start[n] = my; cursor[n] = my; }
}

// ---------------------------------------------------------------------------
// CSR build, step 3: reorder edges by dst into packed (src, weight) int2.
// 2 edges/thread with vector loads.
// ---------------------------------------------------------------------------
__global__ void reorder_kernel(const int* __restrict__ src,
                               const int* __restrict__ dst,
                               const float* __restrict__ w,
                               int* __restrict__ cursor,
                               int2* __restrict__ e_sw) {
    int t = blockIdx.x * blockDim.x + threadIdx.x;
    int e = t * 2;
    if (e + 2 <= NE) {
        int2   s2 = *reinterpret_cast<const int2*>(src + e);
        int2   d2 = *reinterpret_cast<const int2*>(dst + e);
        float2 w2 = *reinterpret_cast<const float2*>(w + e);
        int p0 = atomicAdd(&cursor[d2.x], 1);
        e_sw[p0] = make_int2(s2.x, __float_as_int(w2.x));
        int p1 = atomicAdd(&cursor[d2.y], 1);
        e_sw[p1] = make_int2(s2.y, __float_as_int(w2.y));
    } else {
        for (int i = e; i < NE; ++i) {
            int p = atomicAdd(&cursor[dst[i]], 1);
            e_sw[p] = make_int2(src[i], __float_as_int(w[i]));
        }
    }
}

// ---------------------------------------------------------------------------
// Fused layer: per node n (one wave each, grid-stride):
//   agg[lane] = sum_e w_e * h[src_e][lane]        (gather, coalesced row reads)
//   out[n][lane] = b[lane] + sum_k agg[k]*Wrel[k][lane] + h[n][k]*Wroot[k][lane]
// Dense part uses v_readlane broadcasts against W columns in 128 statically-
// indexed VGPRs, amortized over ~8 nodes/wave. 6144 waves (24/CU) to hide
// random h-row L2/L3 latency (round-7 lesson: 3072 waves = occupancy-starved).
// ---------------------------------------------------------------------------
template<bool LAST>
__global__ void __launch_bounds__(256, 6)
fused_kernel(const float* __restrict__ h,
             const int* __restrict__ row_start,
             const int* __restrict__ deg,
             const int2* __restrict__ e_sw,
             const float* __restrict__ Wrel,
             const float* __restrict__ Wroot,
             const float* __restrict__ b,
             float* __restrict__ hout) {
    const int lane   = threadIdx.x & 63;
    const int wgid   = __builtin_amdgcn_readfirstlane((int)((blockIdx.x * blockDim.x + threadIdx.x) >> 6));
    const int nwaves = (gridDim.x * blockDim.x) >> 6;

    // W columns for this lane -> VGPRs (static indexing via full unroll)
    float w1[DD], w2[DD];
    #pragma unroll
    for (int k = 0; k < DD; ++k) {
        w1[k] = Wrel[k * DD + lane];
        w2[k] = Wroot[k * DD + lane];
    }
    const float bias = b[lane];

    for (int n = wgid; n < NN; n += nwaves) {
        const int beg = row_start[n];
        const int dg  = deg[n];
        const int end = beg + dg;

        // ---- gather ----
        float g0 = 0.f, g1 = 0.f, g2 = 0.f, g3 = 0.f;
        for (int i = beg; i < end; i += 64) {
            int cnt = min(64, end - i);
            int2 e = make_int2(0, 0);
            if (i + lane < end) e = e_sw[i + lane];
            int vs = e.x, vw = e.y;
            int j = 0;
            for (; j + 4 <= cnt; j += 4) {
                int   s0 = rlanei(vs, j+0); float f0 = __int_as_float(rlanei(vw, j+0));
                int   s1 = rlanei(vs, j+1); float f1 = __int_as_float(rlanei(vw, j+1));
                int   s2 = rlanei(vs, j+2); float f2 = __int_as_float(rlanei(vw, j+2));
                int   s3 = rlanei(vs, j+3); float f3 = __int_as_float(rlanei(vw, j+3));
                g0 += f0 * h[(size_t)s0 * DD + lane];
                g1 += f1 * h[(size_t)s1 * DD + lane];
                g2 += f2 * h[(size_t)s2 * DD + lane];
                g3 += f3 * h[(size_t)s3 * DD + lane];
            }
            for (; j < cnt; ++j) {
                int s0 = rlanei(vs, j); float f0 = __int_as_float(rlanei(vw, j));
                g0 += f0 * h[(size_t)s0 * DD + lane];
            }
        }
        const float vagg = (g0 + g1) + (g2 + g3);
        const float vh   = h[(size_t)n * DD + lane];

        // ---- dense: readlane broadcasts x W-in-VGPR ----
        float a0 = bias, a1 = 0.f, a2 = 0.f, a3 = 0.f;
        #pragma unroll
        for (int k = 0; k < DD; k += 2) {
            float sa0 = rlane(vagg, k),     sh0 = rlane(vh, k);
            float sa1 = rlane(vagg, k + 1), sh1 = rlane(vh, k + 1);
            a0 += sa0 * w1[k];
            a1 += sh0 * w2[k];
            a2 += sa1 * w1[k + 1];
            a3 += sh1 * w2[k + 1];
        }
        float r = (a0 + a1) + (a2 + a3);
        if (LAST) r = tanhf(r);
        hout[(size_t)n * DD + lane] = r;
    }
}

extern "C" void kernel_launch(void* const* d_in, const int* in_sizes, int n_in,
                              void* d_out, int out_size, void* d_ws, size_t ws_size,
                              hipStream_t stream) {
    const float* x     = (const float*)d_in[0];
    const int*   ei    = (const int*)d_in[1];
    const float* ew    = (const float*)d_in[2];
    const float* Wrel  = (const float*)d_in[3];
    const float* brel  = (const float*)d_in[4];
    const float* Wroot = (const float*)d_in[5];
    float* out = (float*)d_out;

    // Workspace (~32.6 MB): two h ping-pong buffers (gather reads random rows
    // so layers can NOT run in-place), edge list, CSR meta.
    float* hA        = (float*)d_ws;                    // NN*DD f32
    float* hB        = hA + (size_t)NN * DD;            // NN*DD f32
    int2*  e_sw      = (int2*)(hB + (size_t)NN * DD);   // NE int2
    int*   row_start = (int*)(e_sw + NE);               // NN
    int*   cursor    = row_start + NN;                  // NN
    int*   deg       = cursor + NN;                     // NN
    int*   counter   = deg + NN;                        // 1

    const int* src = ei;            // edge_index[0]
    const int* dst = ei + NE;       // edge_index[1]

    const int hblocks = (NE / 4 + 255) / 256;           // 782  (4 edges/thread)
    const int rblocks = (NE / 2 + 255) / 256;           // 1563 (2 edges/thread)
    const int ablocks = (NN + 255) / 256;               // 196
    const int fblocks = 1536;                           // 6144 waves = 24/CU

    // ---- CSR build ----
    hipMemsetAsync(deg, 0, (size_t)(NN + 1) * sizeof(int), stream); // deg + counter
    hist_kernel<<<hblocks, 256, 0, stream>>>(dst, deg);
    alloc_kernel<<<ablocks, 256, 0, stream>>>(deg, row_start, cursor, counter);
    reorder_kernel<<<rblocks, 256, 0, stream>>>(src, dst, ew, cursor, e_sw);

    // ---- 3 fused layers: x -> hA -> hB -> out ----
    fused_kernel<false><<<fblocks, 256, 0, stream>>>(x,  row_start, deg, e_sw, Wrel,           Wroot,           brel,        hA);
    fused_kernel<false><<<fblocks, 256, 0, stream>>>(hA, row_start, deg, e_sw, Wrel + DD*DD,   Wroot + DD*DD,   brel + DD,   hB);
    fused_kernel<true ><<<fblocks, 256, 0, stream>>>(hB, row_start, deg, e_sw, Wrel + 2*DD*DD, Wroot + 2*DD*DD, brel + 2*DD, out);
}

// Round 9
// 365.876 us; speedup vs baseline: 2.0344x; 2.0344x over previous
//
#include <hip/hip_runtime.h>
#include <hip/hip_bf16.h>

#define NN 50000
#define NE 800000
#define DD 64
#define NL 3

__device__ __forceinline__ int rlanei(int v, int l) {
    return __builtin_amdgcn_readlane(v, l);
}
__device__ __forceinline__ float rlane(float v, int l) {
    return __int_as_float(__builtin_amdgcn_readlane(__float_as_int(v), l));
}

// ---------------------------------------------------------------------------
// CSR build, step 1: in-degree histogram. 4 edges/thread via int4 loads.
// ---------------------------------------------------------------------------
__global__ void hist_kernel(const int* __restrict__ dst, int* __restrict__ deg) {
    int t = blockIdx.x * blockDim.x + threadIdx.x;
    int e = t * 4;
    if (e + 4 <= NE) {
        int4 d4 = *reinterpret_cast<const int4*>(dst + e);
        atomicAdd(&deg[d4.x], 1);
        atomicAdd(&deg[d4.y], 1);
        atomicAdd(&deg[d4.z], 1);
        atomicAdd(&deg[d4.w], 1);
    } else {
        for (int i = e; i < NE; ++i) atomicAdd(&deg[dst[i]], 1);
    }
}

// ---------------------------------------------------------------------------
// CSR build, step 2: unordered segment allocation (order irrelevant for a
// sum): wave-level __shfl_up scan + one atomicAdd per wave on a counter.
// ---------------------------------------------------------------------------
__global__ void alloc_kernel(const int* __restrict__ deg,
                             int* __restrict__ row_start,
                             int* __restrict__ cursor,
                             int* __restrict__ counter) {
    int n = blockIdx.x * blockDim.x + threadIdx.x;
    int lane = threadIdx.x & 63;
    int d = (n < NN) ? deg[n] : 0;
    int s = d;
    #pragma unroll
    for (int off = 1; off < 64; off <<= 1) {
        int t = __shfl_up(s, off);
        if (lane >= off) s += t;
    }
    int total = __shfl(s, 63);
    int base = 0;
    if (lane == 63) base = atomicAdd(counter, total);
    base = __shfl(base, 63);
    int my = base + s - d;
    if (n < NN) { row_start[n] = my; cursor[n] = my; }
}

// ---------------------------------------------------------------------------
// CSR build, step 3: reorder edges by dst into packed (src, weight) int2.
// 2 edges/thread with vector loads.
// ---------------------------------------------------------------------------
__global__ void reorder_kernel(const int* __restrict__ src,
                               const int* __restrict__ dst,
                               const float* __restrict__ w,
                               int* __restrict__ cursor,
                               int2* __restrict__ e_sw) {
    int t = blockIdx.x * blockDim.x + threadIdx.x;
    int e = t * 2;
    if (e + 2 <= NE) {
        int2   s2 = *reinterpret_cast<const int2*>(src + e);
        int2   d2 = *reinterpret_cast<const int2*>(dst + e);
        float2 w2 = *reinterpret_cast<const float2*>(w + e);
        int p0 = atomicAdd(&cursor[d2.x], 1);
        e_sw[p0] = make_int2(s2.x, __float_as_int(w2.x));
        int p1 = atomicAdd(&cursor[d2.y], 1);
        e_sw[p1] = make_int2(s2.y, __float_as_int(w2.y));
    } else {
        for (int i = e; i < NE; ++i) {
            int p = atomicAdd(&cursor[dst[i]], 1);
            e_sw[p] = make_int2(src[i], __float_as_int(w[i]));
        }
    }
}

// ---------------------------------------------------------------------------
// Fused layer: per node n (one wave each, grid-stride):
//   agg[lane] = sum_e w_e * h[src_e][lane]        (gather, coalesced row reads)
//   out[n][lane] = b[lane] + sum_k agg[k]*Wrel[k][lane] + h[n][k]*Wroot[k][lane]
// Dense part uses v_readlane broadcasts against W columns in 128 statically-
// indexed VGPRs. __launch_bounds__(256,3): round-8 lesson — capping tighter
// (256,6) forces VGPR=40 and SPILLS the W arrays to scratch (FETCH 83->542MB,
// 3x slower). (256,3) gives 76 VGPR spill-free, which the HW can still run at
// 6 waves/SIMD; occupancy comes from the 6144-wave grid, not the cap.
// ---------------------------------------------------------------------------
template<bool LAST>
__global__ void __launch_bounds__(256, 3)
fused_kernel(const float* __restrict__ h,
             const int* __restrict__ row_start,
             const int* __restrict__ deg,
             const int2* __restrict__ e_sw,
             const float* __restrict__ Wrel,
             const float* __restrict__ Wroot,
             const float* __restrict__ b,
             float* __restrict__ hout) {
    const int lane   = threadIdx.x & 63;
    const int wgid   = __builtin_amdgcn_readfirstlane((int)((blockIdx.x * blockDim.x + threadIdx.x) >> 6));
    const int nwaves = (gridDim.x * blockDim.x) >> 6;

    // W columns for this lane -> VGPRs (static indexing via full unroll)
    float w1[DD], w2[DD];
    #pragma unroll
    for (int k = 0; k < DD; ++k) {
        w1[k] = Wrel[k * DD + lane];
        w2[k] = Wroot[k * DD + lane];
    }
    const float bias = b[lane];

    for (int n = wgid; n < NN; n += nwaves) {
        const int beg = row_start[n];
        const int dg  = deg[n];
        const int end = beg + dg;

        // ---- gather ----
        float g0 = 0.f, g1 = 0.f, g2 = 0.f, g3 = 0.f;
        for (int i = beg; i < end; i += 64) {
            int cnt = min(64, end - i);
            int2 e = make_int2(0, 0);
            if (i + lane < end) e = e_sw[i + lane];
            int vs = e.x, vw = e.y;
            int j = 0;
            for (; j + 4 <= cnt; j += 4) {
                int   s0 = rlanei(vs, j+0); float f0 = __int_as_float(rlanei(vw, j+0));
                int   s1 = rlanei(vs, j+1); float f1 = __int_as_float(rlanei(vw, j+1));
                int   s2 = rlanei(vs, j+2); float f2 = __int_as_float(rlanei(vw, j+2));
                int   s3 = rlanei(vs, j+3); float f3 = __int_as_float(rlanei(vw, j+3));
                g0 += f0 * h[(size_t)s0 * DD + lane];
                g1 += f1 * h[(size_t)s1 * DD + lane];
                g2 += f2 * h[(size_t)s2 * DD + lane];
                g3 += f3 * h[(size_t)s3 * DD + lane];
            }
            for (; j < cnt; ++j) {
                int s0 = rlanei(vs, j); float f0 = __int_as_float(rlanei(vw, j));
                g0 += f0 * h[(size_t)s0 * DD + lane];
            }
        }
        const float vagg = (g0 + g1) + (g2 + g3);
        const float vh   = h[(size_t)n * DD + lane];

        // ---- dense: readlane broadcasts x W-in-VGPR ----
        float a0 = bias, a1 = 0.f, a2 = 0.f, a3 = 0.f;
        #pragma unroll
        for (int k = 0; k < DD; k += 2) {
            float sa0 = rlane(vagg, k),     sh0 = rlane(vh, k);
            float sa1 = rlane(vagg, k + 1), sh1 = rlane(vh, k + 1);
            a0 += sa0 * w1[k];
            a1 += sh0 * w2[k];
            a2 += sa1 * w1[k + 1];
            a3 += sh1 * w2[k + 1];
        }
        float r = (a0 + a1) + (a2 + a3);
        if (LAST) r = tanhf(r);
        hout[(size_t)n * DD + lane] = r;
    }
}

extern "C" void kernel_launch(void* const* d_in, const int* in_sizes, int n_in,
                              void* d_out, int out_size, void* d_ws, size_t ws_size,
                              hipStream_t stream) {
    const float* x     = (const float*)d_in[0];
    const int*   ei    = (const int*)d_in[1];
    const float* ew    = (const float*)d_in[2];
    const float* Wrel  = (const float*)d_in[3];
    const float* brel  = (const float*)d_in[4];
    const float* Wroot = (const float*)d_in[5];
    float* out = (float*)d_out;

    // Workspace (~32.6 MB): two h ping-pong buffers (gather reads random rows
    // so layers can NOT run in-place), edge list, CSR meta.
    float* hA        = (float*)d_ws;                    // NN*DD f32
    float* hB        = hA + (size_t)NN * DD;            // NN*DD f32
    int2*  e_sw      = (int2*)(hB + (size_t)NN * DD);   // NE int2
    int*   row_start = (int*)(e_sw + NE);               // NN
    int*   cursor    = row_start + NN;                  // NN
    int*   deg       = cursor + NN;                     // NN
    int*   counter   = deg + NN;                        // 1

    const int* src = ei;            // edge_index[0]
    const int* dst = ei + NE;       // edge_index[1]

    const int hblocks = (NE / 4 + 255) / 256;           // 782  (4 edges/thread)
    const int rblocks = (NE / 2 + 255) / 256;           // 1563 (2 edges/thread)
    const int ablocks = (NN + 255) / 256;               // 196
    const int fblocks = 1536;                           // 6144 waves

    // ---- CSR build ----
    hipMemsetAsync(deg, 0, (size_t)(NN + 1) * sizeof(int), stream); // deg + counter
    hist_kernel<<<hblocks, 256, 0, stream>>>(dst, deg);
    alloc_kernel<<<ablocks, 256, 0, stream>>>(deg, row_start, cursor, counter);
    reorder_kernel<<<rblocks, 256, 0, stream>>>(src, dst, ew, cursor, e_sw);

    // ---- 3 fused layers: x -> hA -> hB -> out ----
    fused_kernel<false><<<fblocks, 256, 0, stream>>>(x,  row_start, deg, e_sw, Wrel,           Wroot,           brel,        hA);
    fused_kernel<false><<<fblocks, 256, 0, stream>>>(hA, row_start, deg, e_sw, Wrel + DD*DD,   Wroot + DD*DD,   brel + DD,   hB);
    fused_kernel<true ><<<fblocks, 256, 0, stream>>>(hB, row_start, deg, e_sw, Wrel + 2*DD*DD, Wroot + 2*DD*DD, brel + 2*DD, out);
}

// Round 10
// 362.103 us; speedup vs baseline: 2.0556x; 1.0104x over previous
//
#include <hip/hip_runtime.h>
#include <hip/hip_bf16.h>

#define NN 50000
#define NE 800000
#define DD 64
#define NL 3

__device__ __forceinline__ float rlane(float v, int l) {
    return __int_as_float(__builtin_amdgcn_readlane(__float_as_int(v), l));
}

// ---------------------------------------------------------------------------
// CSR build, step 1: in-degree histogram. 4 edges/thread via int4 loads.
// ---------------------------------------------------------------------------
__global__ void hist_kernel(const int* __restrict__ dst, int* __restrict__ deg) {
    int t = blockIdx.x * blockDim.x + threadIdx.x;
    int e = t * 4;
    if (e + 4 <= NE) {
        int4 d4 = *reinterpret_cast<const int4*>(dst + e);
        atomicAdd(&deg[d4.x], 1);
        atomicAdd(&deg[d4.y], 1);
        atomicAdd(&deg[d4.z], 1);
        atomicAdd(&deg[d4.w], 1);
    } else {
        for (int i = e; i < NE; ++i) atomicAdd(&deg[dst[i]], 1);
    }
}

// ---------------------------------------------------------------------------
// CSR build, step 2: unordered segment allocation: wave scan + 1 atomic/wave.
// ---------------------------------------------------------------------------
__global__ void alloc_kernel(const int* __restrict__ deg,
                             int* __restrict__ row_start,
                             int* __restrict__ cursor,
                             int* __restrict__ counter) {
    int n = blockIdx.x * blockDim.x + threadIdx.x;
    int lane = threadIdx.x & 63;
    int d = (n < NN) ? deg[n] : 0;
    int s = d;
    #pragma unroll
    for (int off = 1; off < 64; off <<= 1) {
        int t = __shfl_up(s, off);
        if (lane >= off) s += t;
    }
    int total = __shfl(s, 63);
    int base = 0;
    if (lane == 63) base = atomicAdd(counter, total);
    base = __shfl(base, 63);
    int my = base + s - d;
    if (n < NN) { row_start[n] = my; cursor[n] = my; }
}

// ---------------------------------------------------------------------------
// CSR build, step 3: reorder edges by dst into packed (src, weight) int2.
// ---------------------------------------------------------------------------
__global__ void reorder_kernel(const int* __restrict__ src,
                               const int* __restrict__ dst,
                               const float* __restrict__ w,
                               int* __restrict__ cursor,
                               int2* __restrict__ e_sw) {
    int t = blockIdx.x * blockDim.x + threadIdx.x;
    int e = t * 2;
    if (e + 2 <= NE) {
        int2   s2 = *reinterpret_cast<const int2*>(src + e);
        int2   d2 = *reinterpret_cast<const int2*>(dst + e);
        float2 w2 = *reinterpret_cast<const float2*>(w + e);
        int p0 = atomicAdd(&cursor[d2.x], 1);
        e_sw[p0] = make_int2(s2.x, __float_as_int(w2.x));
        int p1 = atomicAdd(&cursor[d2.y], 1);
        e_sw[p1] = make_int2(s2.y, __float_as_int(w2.y));
    } else {
        for (int i = e; i < NE; ++i) {
            int p = atomicAdd(&cursor[dst[i]], 1);
            e_sw[p] = make_int2(src[i], __float_as_int(w[i]));
        }
    }
}

// ---------------------------------------------------------------------------
// Gather (DE-FUSED, lean): agg[n][lane] = sum_e w_e * h[src_e][lane].
// One wave per node. No W arrays -> ~45 VGPR; __launch_bounds__(256,8) caps
// at 64 VGPR => 8 waves/SIMD = 32 waves/CU (2x the fused kernel's residency;
// round-9 lesson: fusion's 128 W-VGPRs capped the latency-critical gather at
// 4 waves/SIMD). Unroll-8 independent accumulators for 8-deep load pipeline.
// e_sw reads are wave-uniform (HW broadcast / s_load); h row reads coalesced.
// ---------------------------------------------------------------------------
__global__ void __launch_bounds__(256, 8)
gather_kernel(const float* __restrict__ h,
              const int* __restrict__ row_start,
              const int* __restrict__ deg,
              const int2* __restrict__ e_sw,
              float* __restrict__ agg) {
    int wid = (blockIdx.x * blockDim.x + threadIdx.x) >> 6;
    if (wid >= NN) return;
    int lane = threadIdx.x & 63;
    int beg = row_start[wid];
    int end = beg + deg[wid];
    float a0=0.f,a1=0.f,a2=0.f,a3=0.f,a4=0.f,a5=0.f,a6=0.f,a7=0.f;
    int i = beg;
    for (; i + 8 <= end; i += 8) {
        int2 e0 = e_sw[i+0]; int2 e1 = e_sw[i+1];
        int2 e2 = e_sw[i+2]; int2 e3 = e_sw[i+3];
        int2 e4 = e_sw[i+4]; int2 e5 = e_sw[i+5];
        int2 e6 = e_sw[i+6]; int2 e7 = e_sw[i+7];
        a0 += __int_as_float(e0.y) * h[(size_t)e0.x * DD + lane];
        a1 += __int_as_float(e1.y) * h[(size_t)e1.x * DD + lane];
        a2 += __int_as_float(e2.y) * h[(size_t)e2.x * DD + lane];
        a3 += __int_as_float(e3.y) * h[(size_t)e3.x * DD + lane];
        a4 += __int_as_float(e4.y) * h[(size_t)e4.x * DD + lane];
        a5 += __int_as_float(e5.y) * h[(size_t)e5.x * DD + lane];
        a6 += __int_as_float(e6.y) * h[(size_t)e6.x * DD + lane];
        a7 += __int_as_float(e7.y) * h[(size_t)e7.x * DD + lane];
    }
    for (; i < end; ++i) {
        int2 e = e_sw[i];
        a0 += __int_as_float(e.y) * h[(size_t)e.x * DD + lane];
    }
    agg[(size_t)wid * DD + lane] = ((a0+a1)+(a2+a3)) + ((a4+a5)+(a6+a7));
}

// ---------------------------------------------------------------------------
// Dense: out[n][lane] = b[lane] + sum_k agg[n][k]*Wrel[k][lane]
//                                + h[n][k]*Wroot[k][lane]   (+tanh on last)
// Round-7's proven scheme: W columns in 128 statically-indexed VGPRs,
// readlane broadcasts of the wave-resident agg/h rows. (256,3) = 76 VGPR
// spill-free (round-8 lesson: tighter cap spills W to scratch). Reads only
// row n before writing row n -> in-place safe (hout may equal h).
// ---------------------------------------------------------------------------
template<bool LAST>
__global__ void __launch_bounds__(256, 3)
dense_kernel(const float* __restrict__ agg,
             const float* h,
             const float* __restrict__ Wrel,
             const float* __restrict__ Wroot,
             const float* __restrict__ b,
             float* hout) {
    const int lane   = threadIdx.x & 63;
    const int wgid   = __builtin_amdgcn_readfirstlane((int)((blockIdx.x * blockDim.x + threadIdx.x) >> 6));
    const int nwaves = (gridDim.x * blockDim.x) >> 6;

    float w1[DD], w2[DD];
    #pragma unroll
    for (int k = 0; k < DD; ++k) {
        w1[k] = Wrel[k * DD + lane];
        w2[k] = Wroot[k * DD + lane];
    }
    const float bias = b[lane];

    for (int n = wgid; n < NN; n += nwaves) {
        const float vagg = agg[(size_t)n * DD + lane];
        const float vh   = h[(size_t)n * DD + lane];
        float a0 = bias, a1 = 0.f, a2 = 0.f, a3 = 0.f;
        #pragma unroll
        for (int k = 0; k < DD; k += 2) {
            float sa0 = rlane(vagg, k),     sh0 = rlane(vh, k);
            float sa1 = rlane(vagg, k + 1), sh1 = rlane(vh, k + 1);
            a0 += sa0 * w1[k];
            a1 += sh0 * w2[k];
            a2 += sa1 * w1[k + 1];
            a3 += sh1 * w2[k + 1];
        }
        float r = (a0 + a1) + (a2 + a3);
        if (LAST) r = tanhf(r);
        hout[(size_t)n * DD + lane] = r;
    }
}

extern "C" void kernel_launch(void* const* d_in, const int* in_sizes, int n_in,
                              void* d_out, int out_size, void* d_ws, size_t ws_size,
                              hipStream_t stream) {
    const float* x     = (const float*)d_in[0];
    const int*   ei    = (const int*)d_in[1];
    const float* ew    = (const float*)d_in[2];
    const float* Wrel  = (const float*)d_in[3];
    const float* brel  = (const float*)d_in[4];
    const float* Wroot = (const float*)d_in[5];
    float* out = (float*)d_out;

    // Workspace (~32.6 MB): agg + ONE h buffer (dense is in-place safe) +
    // edge list + CSR meta.
    float* agg       = (float*)d_ws;                    // NN*DD f32
    float* hA        = agg + (size_t)NN * DD;           // NN*DD f32
    int2*  e_sw      = (int2*)(hA + (size_t)NN * DD);   // NE int2
    int*   row_start = (int*)(e_sw + NE);               // NN
    int*   cursor    = row_start + NN;                  // NN
    int*   deg       = cursor + NN;                     // NN
    int*   counter   = deg + NN;                        // 1

    const int* src = ei;            // edge_index[0]
    const int* dst = ei + NE;       // edge_index[1]

    const int hblocks = (NE / 4 + 255) / 256;           // 782
    const int rblocks = (NE / 2 + 255) / 256;           // 1563
    const int ablocks = (NN + 255) / 256;               // 196
    const int gblocks = (NN * 64 + 255) / 256;          // 12500 (1 wave/node)
    const int dblocks = 1024;                           // 4096 waves = 16/CU cap

    // ---- CSR build ----
    hipMemsetAsync(deg, 0, (size_t)(NN + 1) * sizeof(int), stream); // deg + counter
    hist_kernel<<<hblocks, 256, 0, stream>>>(dst, deg);
    alloc_kernel<<<ablocks, 256, 0, stream>>>(deg, row_start, cursor, counter);
    reorder_kernel<<<rblocks, 256, 0, stream>>>(src, dst, ew, cursor, e_sw);

    // ---- 3 layers: gather -> dense (dense in-place on hA) ----
    // l0: x -> agg; dense(agg, x) -> hA
    gather_kernel<<<gblocks, 256, 0, stream>>>(x, row_start, deg, e_sw, agg);
    dense_kernel<false><<<dblocks, 256, 0, stream>>>(agg, x, Wrel, Wroot, brel, hA);
    // l1: hA -> agg; dense(agg, hA) -> hA (in-place)
    gather_kernel<<<gblocks, 256, 0, stream>>>(hA, row_start, deg, e_sw, agg);
    dense_kernel<false><<<dblocks, 256, 0, stream>>>(agg, hA, Wrel + DD*DD, Wroot + DD*DD, brel + DD, hA);
    // l2: hA -> agg; dense(agg, hA) -> out (+tanh)
    gather_kernel<<<gblocks, 256, 0, stream>>>(hA, row_start, deg, e_sw, agg);
    dense_kernel<true ><<<dblocks, 256, 0, stream>>>(agg, hA, Wrel + 2*DD*DD, Wroot + 2*DD*DD, brel + 2*DD, out);
}

// Round 11
// 328.311 us; speedup vs baseline: 2.2672x; 1.1029x over previous
//
#include <hip/hip_runtime.h>
#include <hip/hip_bf16.h>

#define NN 50000
#define NE 800000
#define DD 64
#define NL 3

__device__ __forceinline__ float rlane(float v, int l) {
    return __int_as_float(__builtin_amdgcn_readlane(__float_as_int(v), l));
}

// ---------------------------------------------------------------------------
// CSR build, step 1: in-degree histogram; the atomicAdd RETURN value is the
// edge's rank within its dst segment -> stored contiguously (4B/edge).
// This removes ALL atomics from the reorder step (round-10: reorder's 49us
// was the atomic-ret->store dependent chain).
// ---------------------------------------------------------------------------
__global__ void hist_kernel(const int* __restrict__ dst,
                            int* __restrict__ deg,
                            int* __restrict__ rank) {
    int t = blockIdx.x * blockDim.x + threadIdx.x;
    int e = t * 4;
    if (e + 4 <= NE) {
        int4 d4 = *reinterpret_cast<const int4*>(dst + e);
        int r0 = atomicAdd(&deg[d4.x], 1);
        int r1 = atomicAdd(&deg[d4.y], 1);
        int r2 = atomicAdd(&deg[d4.z], 1);
        int r3 = atomicAdd(&deg[d4.w], 1);
        *reinterpret_cast<int4*>(rank + e) = make_int4(r0, r1, r2, r3);
    } else {
        for (int i = e; i < NE; ++i) rank[i] = atomicAdd(&deg[dst[i]], 1);
    }
}

// ---------------------------------------------------------------------------
// CSR build, step 2: unordered segment allocation: wave scan + 1 atomic/wave.
// ---------------------------------------------------------------------------
__global__ void alloc_kernel(const int* __restrict__ deg,
                             int* __restrict__ row_start,
                             int* __restrict__ counter) {
    int n = blockIdx.x * blockDim.x + threadIdx.x;
    int lane = threadIdx.x & 63;
    int d = (n < NN) ? deg[n] : 0;
    int s = d;
    #pragma unroll
    for (int off = 1; off < 64; off <<= 1) {
        int t = __shfl_up(s, off);
        if (lane >= off) s += t;
    }
    int total = __shfl(s, 63);
    int base = 0;
    if (lane == 63) base = atomicAdd(counter, total);
    base = __shfl(base, 63);
    int my = base + s - d;
    if (n < NN) row_start[n] = my;
}

// ---------------------------------------------------------------------------
// CSR build, step 3: reorder edges into packed (src,weight) int2 at position
// row_start[dst] + rank  -- NO atomics, no dependent chain.
// ---------------------------------------------------------------------------
__global__ void reorder_kernel(const int* __restrict__ src,
                               const int* __restrict__ dst,
                               const float* __restrict__ w,
                               const int* __restrict__ rank,
                               const int* __restrict__ row_start,
                               int2* __restrict__ e_sw) {
    int t = blockIdx.x * blockDim.x + threadIdx.x;
    int e = t * 2;
    if (e + 2 <= NE) {
        int2   s2 = *reinterpret_cast<const int2*>(src + e);
        int2   d2 = *reinterpret_cast<const int2*>(dst + e);
        float2 w2 = *reinterpret_cast<const float2*>(w + e);
        int2   r2 = *reinterpret_cast<const int2*>(rank + e);
        e_sw[row_start[d2.x] + r2.x] = make_int2(s2.x, __float_as_int(w2.x));
        e_sw[row_start[d2.y] + r2.y] = make_int2(s2.y, __float_as_int(w2.y));
    } else {
        for (int i = e; i < NE; ++i) {
            e_sw[row_start[dst[i]] + rank[i]] = make_int2(src[i], __float_as_int(w[i]));
        }
    }
}

// ---------------------------------------------------------------------------
// Gather (lean): agg[n][lane] = sum_e w_e * h[src_e][lane]. One wave/node,
// (256,8) -> <=64 VGPR, 8 waves/SIMD. Unroll-8 independent accumulators.
// UNCHANGED from round 10 (clean A/B; round-10 showed it's bound by random
// L3 row-read traffic, not occupancy).
// ---------------------------------------------------------------------------
__global__ void __launch_bounds__(256, 8)
gather_kernel(const float* __restrict__ h,
              const int* __restrict__ row_start,
              const int* __restrict__ deg,
              const int2* __restrict__ e_sw,
              float* __restrict__ agg) {
    int wid = (blockIdx.x * blockDim.x + threadIdx.x) >> 6;
    if (wid >= NN) return;
    int lane = threadIdx.x & 63;
    int beg = row_start[wid];
    int end = beg + deg[wid];
    float a0=0.f,a1=0.f,a2=0.f,a3=0.f,a4=0.f,a5=0.f,a6=0.f,a7=0.f;
    int i = beg;
    for (; i + 8 <= end; i += 8) {
        int2 e0 = e_sw[i+0]; int2 e1 = e_sw[i+1];
        int2 e2 = e_sw[i+2]; int2 e3 = e_sw[i+3];
        int2 e4 = e_sw[i+4]; int2 e5 = e_sw[i+5];
        int2 e6 = e_sw[i+6]; int2 e7 = e_sw[i+7];
        a0 += __int_as_float(e0.y) * h[(size_t)e0.x * DD + lane];
        a1 += __int_as_float(e1.y) * h[(size_t)e1.x * DD + lane];
        a2 += __int_as_float(e2.y) * h[(size_t)e2.x * DD + lane];
        a3 += __int_as_float(e3.y) * h[(size_t)e3.x * DD + lane];
        a4 += __int_as_float(e4.y) * h[(size_t)e4.x * DD + lane];
        a5 += __int_as_float(e5.y) * h[(size_t)e5.x * DD + lane];
        a6 += __int_as_float(e6.y) * h[(size_t)e6.x * DD + lane];
        a7 += __int_as_float(e7.y) * h[(size_t)e7.x * DD + lane];
    }
    for (; i < end; ++i) {
        int2 e = e_sw[i];
        a0 += __int_as_float(e.y) * h[(size_t)e.x * DD + lane];
    }
    agg[(size_t)wid * DD + lane] = ((a0+a1)+(a2+a3)) + ((a4+a5)+(a6+a7));
}

// ---------------------------------------------------------------------------
// Dense: out[n][lane] = b[lane] + sum_k agg[n][k]*Wrel[k][lane]
//                                + h[n][k]*Wroot[k][lane]   (+tanh on last)
// W columns in 128 statically-indexed VGPRs, readlane broadcasts. (256,3) =
// 76 VGPR spill-free (round-8: tighter cap spills W). In-place safe.
// ---------------------------------------------------------------------------
template<bool LAST>
__global__ void __launch_bounds__(256, 3)
dense_kernel(const float* __restrict__ agg,
             const float* h,
             const float* __restrict__ Wrel,
             const float* __restrict__ Wroot,
             const float* __restrict__ b,
             float* hout) {
    const int lane   = threadIdx.x & 63;
    const int wgid   = __builtin_amdgcn_readfirstlane((int)((blockIdx.x * blockDim.x + threadIdx.x) >> 6));
    const int nwaves = (gridDim.x * blockDim.x) >> 6;

    float w1[DD], w2[DD];
    #pragma unroll
    for (int k = 0; k < DD; ++k) {
        w1[k] = Wrel[k * DD + lane];
        w2[k] = Wroot[k * DD + lane];
    }
    const float bias = b[lane];

    for (int n = wgid; n < NN; n += nwaves) {
        const float vagg = agg[(size_t)n * DD + lane];
        const float vh   = h[(size_t)n * DD + lane];
        float a0 = bias, a1 = 0.f, a2 = 0.f, a3 = 0.f;
        #pragma unroll
        for (int k = 0; k < DD; k += 2) {
            float sa0 = rlane(vagg, k),     sh0 = rlane(vh, k);
            float sa1 = rlane(vagg, k + 1), sh1 = rlane(vh, k + 1);
            a0 += sa0 * w1[k];
            a1 += sh0 * w2[k];
            a2 += sa1 * w1[k + 1];
            a3 += sh1 * w2[k + 1];
        }
        float r = (a0 + a1) + (a2 + a3);
        if (LAST) r = tanhf(r);
        hout[(size_t)n * DD + lane] = r;
    }
}

extern "C" void kernel_launch(void* const* d_in, const int* in_sizes, int n_in,
                              void* d_out, int out_size, void* d_ws, size_t ws_size,
                              hipStream_t stream) {
    const float* x     = (const float*)d_in[0];
    const int*   ei    = (const int*)d_in[1];
    const float* ew    = (const float*)d_in[2];
    const float* Wrel  = (const float*)d_in[3];
    const float* brel  = (const float*)d_in[4];
    const float* Wroot = (const float*)d_in[5];
    float* out = (float*)d_out;

    // Workspace (~35.8 MB; >=45 MB proven available in round 2):
    float* agg       = (float*)d_ws;                    // NN*DD f32 (12.8 MB)
    float* hA        = agg + (size_t)NN * DD;           // NN*DD f32 (12.8 MB)
    int2*  e_sw      = (int2*)(hA + (size_t)NN * DD);   // NE int2   ( 6.4 MB)
    int*   row_start = (int*)(e_sw + NE);               // NN
    int*   deg       = row_start + NN;                  // NN
    int*   counter   = deg + NN;                        // 1
    int*   rank      = counter + 1;                     // NE        ( 3.2 MB)

    const int* src = ei;            // edge_index[0]
    const int* dst = ei + NE;       // edge_index[1]

    const int hblocks = (NE / 4 + 255) / 256;           // 782
    const int rblocks = (NE / 2 + 255) / 256;           // 1563
    const int ablocks = (NN + 255) / 256;               // 196
    const int gblocks = (NN * 64 + 255) / 256;          // 12500 (1 wave/node)
    const int dblocks = 1024;                           // 4096 waves

    // ---- CSR build (reorder is atomic-free via hist ranks) ----
    hipMemsetAsync(deg, 0, (size_t)(NN + 1) * sizeof(int), stream); // deg + counter
    hist_kernel<<<hblocks, 256, 0, stream>>>(dst, deg, rank);
    alloc_kernel<<<ablocks, 256, 0, stream>>>(deg, row_start, counter);
    reorder_kernel<<<rblocks, 256, 0, stream>>>(src, dst, ew, rank, row_start, e_sw);

    // ---- 3 layers: gather -> dense (dense in-place on hA) ----
    gather_kernel<<<gblocks, 256, 0, stream>>>(x, row_start, deg, e_sw, agg);
    dense_kernel<false><<<dblocks, 256, 0, stream>>>(agg, x, Wrel, Wroot, brel, hA);
    gather_kernel<<<gblocks, 256, 0, stream>>>(hA, row_start, deg, e_sw, agg);
    dense_kernel<false><<<dblocks, 256, 0, stream>>>(agg, hA, Wrel + DD*DD, Wroot + DD*DD, brel + DD, hA);
    gather_kernel<<<gblocks, 256, 0, stream>>>(hA, row_start, deg, e_sw, agg);
    dense_kernel<true ><<<dblocks, 256, 0, stream>>>(agg, hA, Wrel + 2*DD*DD, Wroot + 2*DD*DD, brel + 2*DD, out);
}

// Round 12
// 303.483 us; speedup vs baseline: 2.4527x; 1.0818x over previous
//
#include <hip/hip_runtime.h>
#include <hip/hip_bf16.h>

#define NN 50000
#define NE 800000
#define DD 64
#define NL 3
#define NE_PAD (NE + NN * 8)   // worst-case padded edge count (1.2M, 9.6 MB)

__device__ __forceinline__ float rlane(float v, int l) {
    return __int_as_float(__builtin_amdgcn_readlane(__float_as_int(v), l));
}

// ---------------------------------------------------------------------------
// CSR build, step 1: in-degree histogram; atomicAdd return = edge's rank
// within its dst segment (stored contiguously, 4B/edge) -> atomic-free reorder.
// ---------------------------------------------------------------------------
__global__ void hist_kernel(const int* __restrict__ dst,
                            int* __restrict__ deg,
                            int* __restrict__ rank) {
    int t = blockIdx.x * blockDim.x + threadIdx.x;
    int e = t * 4;
    if (e + 4 <= NE) {
        int4 d4 = *reinterpret_cast<const int4*>(dst + e);
        int r0 = atomicAdd(&deg[d4.x], 1);
        int r1 = atomicAdd(&deg[d4.y], 1);
        int r2 = atomicAdd(&deg[d4.z], 1);
        int r3 = atomicAdd(&deg[d4.w], 1);
        *reinterpret_cast<int4*>(rank + e) = make_int4(r0, r1, r2, r3);
    } else {
        for (int i = e; i < NE; ++i) rank[i] = atomicAdd(&deg[dst[i]], 1);
    }
}

// ---------------------------------------------------------------------------
// CSR build, step 2: unordered segment allocation with degrees ROUNDED UP to
// a multiple of 8 (pad slots stay zero from the e_sw memset -> (src=0,w=0.0)
// no-op edges). Gather then runs a pure unroll-8 loop with NO serial tail.
// ---------------------------------------------------------------------------
__global__ void alloc_kernel(const int* __restrict__ deg,
                             int* __restrict__ row_start,
                             int* __restrict__ counter) {
    int n = blockIdx.x * blockDim.x + threadIdx.x;
    int lane = threadIdx.x & 63;
    int d = (n < NN) ? ((deg[n] + 7) & ~7) : 0;   // rounded allocation
    int s = d;
    #pragma unroll
    for (int off = 1; off < 64; off <<= 1) {
        int t = __shfl_up(s, off);
        if (lane >= off) s += t;
    }
    int total = __shfl(s, 63);
    int base = 0;
    if (lane == 63) base = atomicAdd(counter, total);
    base = __shfl(base, 63);
    int my = base + s - d;
    if (n < NN) row_start[n] = my;
}

// ---------------------------------------------------------------------------
// CSR build, step 3: reorder edges to row_start[dst] + rank -- no atomics.
// ---------------------------------------------------------------------------
__global__ void reorder_kernel(const int* __restrict__ src,
                               const int* __restrict__ dst,
                               const float* __restrict__ w,
                               const int* __restrict__ rank,
                               const int* __restrict__ row_start,
                               int2* __restrict__ e_sw) {
    int t = blockIdx.x * blockDim.x + threadIdx.x;
    int e = t * 2;
    if (e + 2 <= NE) {
        int2   s2 = *reinterpret_cast<const int2*>(src + e);
        int2   d2 = *reinterpret_cast<const int2*>(dst + e);
        float2 w2 = *reinterpret_cast<const float2*>(w + e);
        int2   r2 = *reinterpret_cast<const int2*>(rank + e);
        e_sw[row_start[d2.x] + r2.x] = make_int2(s2.x, __float_as_int(w2.x));
        e_sw[row_start[d2.y] + r2.y] = make_int2(s2.y, __float_as_int(w2.y));
    } else {
        for (int i = e; i < NE; ++i) {
            e_sw[row_start[dst[i]] + rank[i]] = make_int2(src[i], __float_as_int(w[i]));
        }
    }
}

// ---------------------------------------------------------------------------
// Gather: agg[n][lane] = sum_e w_e * h[src_e][lane]. One wave/node, (256,8)
// -> <=64 VGPR, 8 waves/SIMD. Round-11 changes: (a) segments padded to x8 so
// the unroll-8 pipeline has NO serial tail; (b) beg/rdeg/wid readfirstlane'd
// so e_sw loads go down the SCALAR path (s_load, 64B/iter), keeping the
// vector-memory pipe exclusively for the random h-row reads.
// ---------------------------------------------------------------------------
__global__ void __launch_bounds__(256, 8)
gather_kernel(const float* __restrict__ h,
              const int* __restrict__ row_start,
              const int* __restrict__ deg,
              const int2* __restrict__ e_sw,
              float* __restrict__ agg) {
    int wid = __builtin_amdgcn_readfirstlane((int)((blockIdx.x * blockDim.x + threadIdx.x) >> 6));
    if (wid >= NN) return;
    int lane = threadIdx.x & 63;
    int beg  = __builtin_amdgcn_readfirstlane(row_start[wid]);
    int rdeg = __builtin_amdgcn_readfirstlane((deg[wid] + 7) & ~7);
    float a0=0.f,a1=0.f,a2=0.f,a3=0.f,a4=0.f,a5=0.f,a6=0.f,a7=0.f;
    for (int i = 0; i < rdeg; i += 8) {
        const int2* ep = e_sw + beg + i;
        int2 e0 = ep[0]; int2 e1 = ep[1];
        int2 e2 = ep[2]; int2 e3 = ep[3];
        int2 e4 = ep[4]; int2 e5 = ep[5];
        int2 e6 = ep[6]; int2 e7 = ep[7];
        a0 += __int_as_float(e0.y) * h[(size_t)e0.x * DD + lane];
        a1 += __int_as_float(e1.y) * h[(size_t)e1.x * DD + lane];
        a2 += __int_as_float(e2.y) * h[(size_t)e2.x * DD + lane];
        a3 += __int_as_float(e3.y) * h[(size_t)e3.x * DD + lane];
        a4 += __int_as_float(e4.y) * h[(size_t)e4.x * DD + lane];
        a5 += __int_as_float(e5.y) * h[(size_t)e5.x * DD + lane];
        a6 += __int_as_float(e6.y) * h[(size_t)e6.x * DD + lane];
        a7 += __int_as_float(e7.y) * h[(size_t)e7.x * DD + lane];
    }
    agg[(size_t)wid * DD + lane] = ((a0+a1)+(a2+a3)) + ((a4+a5)+(a6+a7));
}

// ---------------------------------------------------------------------------
// Dense: out[n][lane] = b[lane] + sum_k agg[n][k]*Wrel[k][lane]
//                                + h[n][k]*Wroot[k][lane]   (+tanh on last)
// W columns in 128 statically-indexed VGPRs, readlane broadcasts. (256,3) =
// 76 VGPR spill-free (round-8: tighter cap spills W). In-place safe.
// ---------------------------------------------------------------------------
template<bool LAST>
__global__ void __launch_bounds__(256, 3)
dense_kernel(const float* __restrict__ agg,
             const float* h,
             const float* __restrict__ Wrel,
             const float* __restrict__ Wroot,
             const float* __restrict__ b,
             float* hout) {
    const int lane   = threadIdx.x & 63;
    const int wgid   = __builtin_amdgcn_readfirstlane((int)((blockIdx.x * blockDim.x + threadIdx.x) >> 6));
    const int nwaves = (gridDim.x * blockDim.x) >> 6;

    float w1[DD], w2[DD];
    #pragma unroll
    for (int k = 0; k < DD; ++k) {
        w1[k] = Wrel[k * DD + lane];
        w2[k] = Wroot[k * DD + lane];
    }
    const float bias = b[lane];

    for (int n = wgid; n < NN; n += nwaves) {
        const float vagg = agg[(size_t)n * DD + lane];
        const float vh   = h[(size_t)n * DD + lane];
        float a0 = bias, a1 = 0.f, a2 = 0.f, a3 = 0.f;
        #pragma unroll
        for (int k = 0; k < DD; k += 2) {
            float sa0 = rlane(vagg, k),     sh0 = rlane(vh, k);
            float sa1 = rlane(vagg, k + 1), sh1 = rlane(vh, k + 1);
            a0 += sa0 * w1[k];
            a1 += sh0 * w2[k];
            a2 += sa1 * w1[k + 1];
            a3 += sh1 * w2[k + 1];
        }
        float r = (a0 + a1) + (a2 + a3);
        if (LAST) r = tanhf(r);
        hout[(size_t)n * DD + lane] = r;
    }
}

extern "C" void kernel_launch(void* const* d_in, const int* in_sizes, int n_in,
                              void* d_out, int out_size, void* d_ws, size_t ws_size,
                              hipStream_t stream) {
    const float* x     = (const float*)d_in[0];
    const int*   ei    = (const int*)d_in[1];
    const float* ew    = (const float*)d_in[2];
    const float* Wrel  = (const float*)d_in[3];
    const float* brel  = (const float*)d_in[4];
    const float* Wroot = (const float*)d_in[5];
    float* out = (float*)d_out;

    // Workspace (~39 MB of the 256 MiB ws):
    float* agg       = (float*)d_ws;                    // NN*DD f32 (12.8 MB)
    float* hA        = agg + (size_t)NN * DD;           // NN*DD f32 (12.8 MB)
    int2*  e_sw      = (int2*)(hA + (size_t)NN * DD);   // NE_PAD int2 (9.6 MB)
    int*   row_start = (int*)(e_sw + NE_PAD);           // NN
    int*   deg       = row_start + NN;                  // NN
    int*   counter   = deg + NN;                        // 1
    int*   rank      = counter + 1;                     // NE (3.2 MB)

    const int* src = ei;            // edge_index[0]
    const int* dst = ei + NE;       // edge_index[1]

    const int hblocks = (NE / 4 + 255) / 256;           // 782
    const int rblocks = (NE / 2 + 255) / 256;           // 1563
    const int ablocks = (NN + 255) / 256;               // 196
    const int gblocks = (NN * 64 + 255) / 256;          // 12500 (1 wave/node)
    const int dblocks = 1024;                           // 4096 waves

    // ---- CSR build (padded segments; zeroed e_sw supplies no-op pad edges) ----
    hipMemsetAsync(deg, 0, (size_t)(NN + 1) * sizeof(int), stream);   // deg + counter
    hipMemsetAsync(e_sw, 0, (size_t)NE_PAD * sizeof(int2), stream);   // pad slots = (0, 0.0f)
    hist_kernel<<<hblocks, 256, 0, stream>>>(dst, deg, rank);
    alloc_kernel<<<ablocks, 256, 0, stream>>>(deg, row_start, counter);
    reorder_kernel<<<rblocks, 256, 0, stream>>>(src, dst, ew, rank, row_start, e_sw);

    // ---- 3 layers: gather -> dense (dense in-place on hA) ----
    gather_kernel<<<gblocks, 256, 0, stream>>>(x, row_start, deg, e_sw, agg);
    dense_kernel<false><<<dblocks, 256, 0, stream>>>(agg, x, Wrel, Wroot, brel, hA);
    gather_kernel<<<gblocks, 256, 0, stream>>>(hA, row_start, deg, e_sw, agg);
    dense_kernel<false><<<dblocks, 256, 0, stream>>>(agg, hA, Wrel + DD*DD, Wroot + DD*DD, brel + DD, hA);
    gather_kernel<<<gblocks, 256, 0, stream>>>(hA, row_start, deg, e_sw, agg);
    dense_kernel<true ><<<dblocks, 256, 0, stream>>>(agg, hA, Wrel + 2*DD*DD, Wroot + 2*DD*DD, brel + 2*DD, out);
}

// Round 13
// 302.560 us; speedup vs baseline: 2.4602x; 1.0031x over previous
//
#include <hip/hip_runtime.h>
#include <hip/hip_bf16.h>

#define NN 50000
#define NE 800000
#define DD 64
#define NL 3
#define NE_PAD (NE + NN * 16)   // worst-case padded edge count (1.6M, 12.8 MB)

__device__ __forceinline__ float rlane(float v, int l) {
    return __int_as_float(__builtin_amdgcn_readlane(__float_as_int(v), l));
}

// ---------------------------------------------------------------------------
// CSR build, step 1: in-degree histogram; atomicAdd return = edge's rank
// within its dst segment (stored contiguously) -> atomic-free reorder.
// ---------------------------------------------------------------------------
__global__ void hist_kernel(const int* __restrict__ dst,
                            int* __restrict__ deg,
                            int* __restrict__ rank) {
    int t = blockIdx.x * blockDim.x + threadIdx.x;
    int e = t * 4;
    if (e + 4 <= NE) {
        int4 d4 = *reinterpret_cast<const int4*>(dst + e);
        int r0 = atomicAdd(&deg[d4.x], 1);
        int r1 = atomicAdd(&deg[d4.y], 1);
        int r2 = atomicAdd(&deg[d4.z], 1);
        int r3 = atomicAdd(&deg[d4.w], 1);
        *reinterpret_cast<int4*>(rank + e) = make_int4(r0, r1, r2, r3);
    } else {
        for (int i = e; i < NE; ++i) rank[i] = atomicAdd(&deg[dst[i]], 1);
    }
}

// ---------------------------------------------------------------------------
// CSR build, step 2: unordered segment allocation, degrees rounded up to x16
// (pad slots stay zero from the e_sw memset -> (src=0, w=0.0) no-op edges).
// ---------------------------------------------------------------------------
__global__ void alloc_kernel(const int* __restrict__ deg,
                             int* __restrict__ row_start,
                             int* __restrict__ counter) {
    int n = blockIdx.x * blockDim.x + threadIdx.x;
    int lane = threadIdx.x & 63;
    int d = (n < NN) ? ((deg[n] + 15) & ~15) : 0;
    int s = d;
    #pragma unroll
    for (int off = 1; off < 64; off <<= 1) {
        int t = __shfl_up(s, off);
        if (lane >= off) s += t;
    }
    int total = __shfl(s, 63);
    int base = 0;
    if (lane == 63) base = atomicAdd(counter, total);
    base = __shfl(base, 63);
    int my = base + s - d;
    if (n < NN) row_start[n] = my;
}

// ---------------------------------------------------------------------------
// CSR build, step 3: reorder edges to row_start[dst] + rank -- no atomics.
// ---------------------------------------------------------------------------
__global__ void reorder_kernel(const int* __restrict__ src,
                               const int* __restrict__ dst,
                               const float* __restrict__ w,
                               const int* __restrict__ rank,
                               const int* __restrict__ row_start,
                               int2* __restrict__ e_sw) {
    int t = blockIdx.x * blockDim.x + threadIdx.x;
    int e = t * 2;
    if (e + 2 <= NE) {
        int2   s2 = *reinterpret_cast<const int2*>(src + e);
        int2   d2 = *reinterpret_cast<const int2*>(dst + e);
        float2 w2 = *reinterpret_cast<const float2*>(w + e);
        int2   r2 = *reinterpret_cast<const int2*>(rank + e);
        e_sw[row_start[d2.x] + r2.x] = make_int2(s2.x, __float_as_int(w2.x));
        e_sw[row_start[d2.y] + r2.y] = make_int2(s2.y, __float_as_int(w2.y));
    } else {
        for (int i = e; i < NE; ++i) {
            e_sw[row_start[dst[i]] + rank[i]] = make_int2(src[i], __float_as_int(w[i]));
        }
    }
}

// ---------------------------------------------------------------------------
// Gather, 4-rows-per-instruction: lane L reads float4 (16B) of row
// src[edge(L>>4)] at columns (L&15)*4 -> one global_load_dwordx4 covers 4
// edges (1KB). 4x bytes-in-flight per vmcnt slot vs the 1-row/inst version
// (round-12 diagnosis: gather is MLP-limited on the random L2-miss path).
// Edge meta s_loaded (uniform addr), distributed to lane-groups via cndmask
// chains (no runtime-indexed arrays). Epilogue: shfl_xor(16/32) butterfly,
// lanes 0-15 store the 256B row. Segments padded to x16 -> no tails.
// ---------------------------------------------------------------------------
__global__ void __launch_bounds__(256, 8)
gather_kernel(const float* __restrict__ h,
              const int* __restrict__ row_start,
              const int* __restrict__ deg,
              const int2* __restrict__ e_sw,
              float* __restrict__ agg) {
    int wid = __builtin_amdgcn_readfirstlane((int)((blockIdx.x * blockDim.x + threadIdx.x) >> 6));
    if (wid >= NN) return;
    const int lane = threadIdx.x & 63;
    const int g    = lane >> 4;          // edge sub-group 0..3
    const int cq   = (lane & 15) << 2;   // this lane's 4-column base
    const int beg  = __builtin_amdgcn_readfirstlane(row_start[wid]);
    const int rdeg = __builtin_amdgcn_readfirstlane((deg[wid] + 15) & ~15);

    float ax0=0.f, ay0=0.f, az0=0.f, aw0=0.f;
    float ax1=0.f, ay1=0.f, az1=0.f, aw1=0.f;
    float ax2=0.f, ay2=0.f, az2=0.f, aw2=0.f;
    float ax3=0.f, ay3=0.f, az3=0.f, aw3=0.f;

    for (int i = 0; i < rdeg; i += 16) {
        const int2* ep = e_sw + beg + i;       // uniform -> s_load path
        int2 m0 = ep[0],  m1 = ep[1],  m2 = ep[2],  m3 = ep[3];
        int2 m4 = ep[4],  m5 = ep[5],  m6 = ep[6],  m7 = ep[7];
        int2 m8 = ep[8],  m9 = ep[9],  m10= ep[10], m11= ep[11];
        int2 m12= ep[12], m13= ep[13], m14= ep[14], m15= ep[15];

#define SLOT(AX,AY,AZ,AW, EA,EB,EC,ED)                                          \
        {                                                                       \
            int  srcg = (g==0) ? EA.x : (g==1) ? EB.x : (g==2) ? EC.x : ED.x;   \
            int  wig  = (g==0) ? EA.y : (g==1) ? EB.y : (g==2) ? EC.y : ED.y;   \
            float wg  = __int_as_float(wig);                                    \
            const float4 r = *reinterpret_cast<const float4*>(                  \
                h + (size_t)srcg * DD + cq);                                    \
            AX += wg * r.x; AY += wg * r.y; AZ += wg * r.z; AW += wg * r.w;     \
        }
        SLOT(ax0,ay0,az0,aw0, m0,m1,m2,m3)
        SLOT(ax1,ay1,az1,aw1, m4,m5,m6,m7)
        SLOT(ax2,ay2,az2,aw2, m8,m9,m10,m11)
        SLOT(ax3,ay3,az3,aw3, m12,m13,m14,m15)
#undef SLOT
    }

    // combine unroll slots (same columns, different edges)
    float tx = (ax0+ax1)+(ax2+ax3);
    float ty = (ay0+ay1)+(ay2+ay3);
    float tz = (az0+az1)+(az2+az3);
    float tw = (aw0+aw1)+(aw2+aw3);
    // reduce across the 4 lane-groups (stride 16 butterfly)
    tx += __shfl_xor(tx, 16); tx += __shfl_xor(tx, 32);
    ty += __shfl_xor(ty, 16); ty += __shfl_xor(ty, 32);
    tz += __shfl_xor(tz, 16); tz += __shfl_xor(tz, 32);
    tw += __shfl_xor(tw, 16); tw += __shfl_xor(tw, 32);

    if (lane < 16) {
        float4 t = make_float4(tx, ty, tz, tw);
        *reinterpret_cast<float4*>(agg + (size_t)wid * DD + cq) = t;
    }
}

// ---------------------------------------------------------------------------
// Dense: out[n][lane] = b[lane] + sum_k agg[n][k]*Wrel[k][lane]
//                                + h[n][k]*Wroot[k][lane]   (+tanh on last)
// W columns in 128 statically-indexed VGPRs, readlane broadcasts. (256,3) =
// 76 VGPR spill-free (round-8: tighter cap spills W). In-place safe.
// ---------------------------------------------------------------------------
template<bool LAST>
__global__ void __launch_bounds__(256, 3)
dense_kernel(const float* __restrict__ agg,
             const float* h,
             const float* __restrict__ Wrel,
             const float* __restrict__ Wroot,
             const float* __restrict__ b,
             float* hout) {
    const int lane   = threadIdx.x & 63;
    const int wgid   = __builtin_amdgcn_readfirstlane((int)((blockIdx.x * blockDim.x + threadIdx.x) >> 6));
    const int nwaves = (gridDim.x * blockDim.x) >> 6;

    float w1[DD], w2[DD];
    #pragma unroll
    for (int k = 0; k < DD; ++k) {
        w1[k] = Wrel[k * DD + lane];
        w2[k] = Wroot[k * DD + lane];
    }
    const float bias = b[lane];

    for (int n = wgid; n < NN; n += nwaves) {
        const float vagg = agg[(size_t)n * DD + lane];
        const float vh   = h[(size_t)n * DD + lane];
        float a0 = bias, a1 = 0.f, a2 = 0.f, a3 = 0.f;
        #pragma unroll
        for (int k = 0; k < DD; k += 2) {
            float sa0 = rlane(vagg, k),     sh0 = rlane(vh, k);
            float sa1 = rlane(vagg, k + 1), sh1 = rlane(vh, k + 1);
            a0 += sa0 * w1[k];
            a1 += sh0 * w2[k];
            a2 += sa1 * w1[k + 1];
            a3 += sh1 * w2[k + 1];
        }
        float r = (a0 + a1) + (a2 + a3);
        if (LAST) r = tanhf(r);
        hout[(size_t)n * DD + lane] = r;
    }
}

extern "C" void kernel_launch(void* const* d_in, const int* in_sizes, int n_in,
                              void* d_out, int out_size, void* d_ws, size_t ws_size,
                              hipStream_t stream) {
    const float* x     = (const float*)d_in[0];
    const int*   ei    = (const int*)d_in[1];
    const float* ew    = (const float*)d_in[2];
    const float* Wrel  = (const float*)d_in[3];
    const float* brel  = (const float*)d_in[4];
    const float* Wroot = (const float*)d_in[5];
    float* out = (float*)d_out;

    // Workspace (~42 MB of 256 MiB):
    float* agg       = (float*)d_ws;                    // NN*DD f32 (12.8 MB)
    float* hA        = agg + (size_t)NN * DD;           // NN*DD f32 (12.8 MB)
    int2*  e_sw      = (int2*)(hA + (size_t)NN * DD);   // NE_PAD int2 (12.8 MB)
    int*   row_start = (int*)(e_sw + NE_PAD);           // NN
    int*   deg       = row_start + NN;                  // NN
    int*   counter   = deg + NN;                        // 1
    int*   rank      = counter + 1;                     // NE (3.2 MB)

    const int* src = ei;            // edge_index[0]
    const int* dst = ei + NE;       // edge_index[1]

    const int hblocks = (NE / 4 + 255) / 256;           // 782
    const int rblocks = (NE / 2 + 255) / 256;           // 1563
    const int ablocks = (NN + 255) / 256;               // 196
    const int gblocks = (NN * 64 + 255) / 256;          // 12500 (1 wave/node)
    const int dblocks = 1024;                           // 4096 waves

    // ---- CSR build (padded segments; zeroed e_sw supplies no-op pad edges) ----
    hipMemsetAsync(deg, 0, (size_t)(NN + 1) * sizeof(int), stream);   // deg + counter
    hipMemsetAsync(e_sw, 0, (size_t)NE_PAD * sizeof(int2), stream);   // pad = (0, 0.0f)
    hist_kernel<<<hblocks, 256, 0, stream>>>(dst, deg, rank);
    alloc_kernel<<<ablocks, 256, 0, stream>>>(deg, row_start, counter);
    reorder_kernel<<<rblocks, 256, 0, stream>>>(src, dst, ew, rank, row_start, e_sw);

    // ---- 3 layers: gather -> dense (dense in-place on hA) ----
    gather_kernel<<<gblocks, 256, 0, stream>>>(x, row_start, deg, e_sw, agg);
    dense_kernel<false><<<dblocks, 256, 0, stream>>>(agg, x, Wrel, Wroot, brel, hA);
    gather_kernel<<<gblocks, 256, 0, stream>>>(hA, row_start, deg, e_sw, agg);
    dense_kernel<false><<<dblocks, 256, 0, stream>>>(agg, hA, Wrel + DD*DD, Wroot + DD*DD, brel + DD, hA);
    gather_kernel<<<gblocks, 256, 0, stream>>>(hA, row_start, deg, e_sw, agg);
    dense_kernel<true ><<<dblocks, 256, 0, stream>>>(agg, hA, Wrel + 2*DD*DD, Wroot + 2*DD*DD, brel + 2*DD, out);
}